// Round 1
// baseline (57.965 us; speedup 1.0000x reference)
//
#include <hip/hip_runtime.h>

#define BC 88                       // B*C channels
#define NVOX 262144                 // 64^3
#define KBINS 20
#define SPLIT 32                    // blocks per channel
#define THREADS 256
#define EPB (NVOX / SPLIT)          // 8192 elements per block
#define V4PT (EPB / (THREADS * 4))  // 8 float4 per thread
#define NSUB 16                     // LDS sub-histograms
#define NBLOCKS (BC * SPLIT)        // 2816

// Exact bin lookup: arithmetic candidate, corrected against the real edge
// array so edge-rounding matches the JAX reference exactly.
__device__ __forceinline__ int bin_of(float x, const float* se, float se0, float inv_w) {
    int k = (int)floorf((x - se0) * inv_w);
    if (k < -1 || k > KBINS) return -1;
    if (k >= 0 && k < KBINS) { if (x >= se[k] && x < se[k + 1]) return k; }
    if (k >= 1)              { if (x >= se[k - 1] && x < se[k]) return k - 1; }
    if (k + 1 < KBINS && k >= -1) { if (x >= se[k + 1] && x < se[k + 2]) return k + 1; }
    return -1;
}

extern "C" __global__ void __launch_bounds__(THREADS)
binloss_main(const float* __restrict__ inp, const float* __restrict__ tar,
             const float* __restrict__ br, int* __restrict__ g_hist,
             float* __restrict__ partials)
{
    __shared__ int   sh[NSUB * KBINS];
    __shared__ float se[KBINS + 1];
    __shared__ float wsum[THREADS / 64];

    const int tid = threadIdx.x;
    for (int i = tid; i < NSUB * KBINS; i += THREADS) sh[i] = 0;
    if (tid <= KBINS) se[tid] = (tid < KBINS) ? br[2 * tid] : br[2 * KBINS - 1];
    __syncthreads();

    const float se0   = se[0];
    const float inv_w = (float)KBINS / (se[KBINS] - se0);

    const int bid = blockIdx.x;
    const int ch  = bid >> 5;           // / SPLIT
    const int s   = bid & (SPLIT - 1);
    const size_t base = (size_t)ch * NVOX + (size_t)s * EPB;
    const float4* ip = (const float4*)(inp + base);
    const float4* tp = (const float4*)(tar + base);

    int* myh = &sh[(tid & (NSUB - 1)) * KBINS];
    float sl1 = 0.f;

#pragma unroll
    for (int j = 0; j < V4PT; ++j) {
        float4 a = ip[j * THREADS + tid];
        float4 b = tp[j * THREADS + tid];
#pragma unroll
        for (int c = 0; c < 4; ++c) {
            float av = (&a.x)[c], bv = (&b.x)[c];
            float d = fabsf(av - bv);
            sl1 += (d < 1.f) ? 0.5f * d * d : (d - 0.5f);
            int ka = bin_of(av, se, se0, inv_w);
            int kb = bin_of(bv, se, se0, inv_w);
            if (ka != kb) {                  // equal bins cancel in the diff-hist
                if (ka >= 0) atomicAdd(&myh[ka], 1);
                if (kb >= 0) atomicAdd(&myh[kb], -1);
            }
        }
    }

    // wave(64)-level + cross-wave reduction of the SmoothL1 partial
    for (int off = 32; off > 0; off >>= 1) sl1 += __shfl_down(sl1, off, 64);
    if ((tid & 63) == 0) wsum[tid >> 6] = sl1;
    __syncthreads();
    if (tid == 0) {
        float tot = 0.f;
        for (int w = 0; w < THREADS / 64; ++w) tot += wsum[w];
        partials[bid] = tot;
    }

    // fold 16 sub-histograms -> one global int atomic per bin
    for (int k = tid; k < KBINS; k += THREADS) {
        int t = 0;
#pragma unroll
        for (int h = 0; h < NSUB; ++h) t += sh[h * KBINS + k];
        atomicAdd(&g_hist[ch * KBINS + k], t);
    }
}

extern "C" __global__ void __launch_bounds__(256)
binloss_final(const int* __restrict__ g_hist, const float* __restrict__ partials,
              float* __restrict__ out)
{
    __shared__ double r1[256];
    __shared__ double r2[256];
    const int tid = threadIdx.x;
    double s1 = 0.0, s2 = 0.0;
    for (int i = tid; i < NBLOCKS; i += 256) s1 += (double)partials[i];
    for (int i = tid; i < BC * KBINS; i += 256) s2 += fabs((double)g_hist[i]);
    r1[tid] = s1; r2[tid] = s2;
    __syncthreads();
    for (int off = 128; off > 0; off >>= 1) {
        if (tid < off) { r1[tid] += r1[tid + off]; r2[tid] += r2[tid + off]; }
        __syncthreads();
    }
    if (tid == 0) {
        const double ntot  = (double)BC * (double)NVOX;
        double loss1 = r1[0] / ntot;
        double loss2 = r2[0] / ((double)NVOX * (double)(BC * KBINS));
        out[0] = (float)(0.5 * loss1 + 0.5 * loss2);
    }
}

extern "C" void kernel_launch(void* const* d_in, const int* in_sizes, int n_in,
                              void* d_out, int out_size, void* d_ws, size_t ws_size,
                              hipStream_t stream) {
    const float* inp = (const float*)d_in[0];
    const float* tar = (const float*)d_in[1];
    const float* br  = (const float*)d_in[2];

    int*   g_hist   = (int*)d_ws;
    float* partials = (float*)((char*)d_ws + BC * KBINS * sizeof(int));

    // histogram is accumulated with atomics -> must be zeroed every call
    hipMemsetAsync(d_ws, 0, BC * KBINS * sizeof(int), stream);

    binloss_main<<<NBLOCKS, THREADS, 0, stream>>>(inp, tar, br, g_hist, partials);
    binloss_final<<<1, 256, 0, stream>>>(g_hist, partials, (float*)d_out);
}

// Round 2
// 44.824 us; speedup vs baseline: 1.2932x; 1.2932x over previous
//
#include <hip/hip_runtime.h>

#define BC 88                       // B*C channels
#define NVOX 262144                 // 64^3
#define KBINS 20
#define SPLIT 32                    // blocks per channel
#define THREADS 256
#define EPB (NVOX / SPLIT)          // 8192 element-pairs per block
#define V4PT (EPB / (THREADS * 4))  // 8 float4 per thread
#define NSUB 64                     // one sub-histogram per lane id
#define HSTRIDE 23                  // 22 slots (trash at 0 and 21) + pad; gcd(23,32)=1
#define NBLOCKS (BC * SPLIT)        // 2816

__global__ void __launch_bounds__(THREADS)
binloss_main(const float* __restrict__ inp, const float* __restrict__ tar,
             const float* __restrict__ br, int* __restrict__ g_hist,
             float* __restrict__ partials)
{
    __shared__ int   sh[NSUB * HSTRIDE];
    __shared__ float wsum[THREADS / 64];

    const int tid = threadIdx.x;
    for (int i = tid; i < NSUB * HSTRIDE; i += THREADS) sh[i] = 0;

    // Bins are contiguous and uniform (linspace): derive affine map from the
    // first/last edge (uniform-address loads -> s_load, negligible).
    const float e0    = br[0];
    const float eK    = br[2 * KBINS - 1];
    const float inv_w = (float)KBINS / (eK - e0);
    const float shift = -e0 * inv_w;
    __syncthreads();

    const int bid = blockIdx.x;
    const int ch  = bid >> 5;           // / SPLIT
    const int s   = bid & (SPLIT - 1);
    const size_t base = (size_t)ch * NVOX + (size_t)s * EPB;
    const float4* ip = (const float4*)(inp + base);
    const float4* tp = (const float4*)(tar + base);

    int* myh = &sh[(tid & 63) * HSTRIDE];   // per-lane private sub-histogram
    float s_lin = 0.f, s_quad = 0.f;

#pragma unroll
    for (int j = 0; j < V4PT; ++j) {
        float4 a = ip[j * THREADS + tid];
        float4 b = tp[j * THREADS + tid];
#pragma unroll
        for (int c = 0; c < 4; ++c) {
            float av = (&a.x)[c], bv = (&b.x)[c];
            // SmoothL1, branch-free: d<1 ? 0.5 d^2 : d-0.5  ==  (d-m) + 0.5 m^2, m=min(d,1)
            float d = fabsf(av - bv);
            float m = fminf(d, 1.0f);
            s_lin += d - m;
            s_quad = __builtin_fmaf(m, m, s_quad);
            // Arithmetic bin: clamp to [-1, K+0.5) via med3 -> slots 0..K+1,
            // 0 and K+1 are trash (x outside [e0,eK)). Signed diff-histogram.
            float ta = __builtin_amdgcn_fmed3f(__builtin_fmaf(av, inv_w, shift), -1.0f, (float)KBINS + 0.5f);
            float tb = __builtin_amdgcn_fmed3f(__builtin_fmaf(bv, inv_w, shift), -1.0f, (float)KBINS + 0.5f);
            int ka = (int)floorf(ta);
            int kb = (int)floorf(tb);
            atomicAdd(&myh[ka + 1], 1);
            atomicAdd(&myh[kb + 1], -1);
        }
    }

    // wave(64) + cross-wave reduction of the SmoothL1 partial
    float sl1 = s_lin + 0.5f * s_quad;
    for (int off = 32; off > 0; off >>= 1) sl1 += __shfl_down(sl1, off, 64);
    if ((tid & 63) == 0) wsum[tid >> 6] = sl1;
    __syncthreads();
    if (tid == 0) {
        float tot = 0.f;
        for (int w = 0; w < THREADS / 64; ++w) tot += wsum[w];
        partials[bid] = tot;
    }

    // fold 64 sub-histograms (slots 1..K) -> one global int atomic per bin
    for (int k = 1 + tid; k <= KBINS; k += THREADS) {
        int t = 0;
#pragma unroll
        for (int h = 0; h < NSUB; ++h) t += sh[h * HSTRIDE + k];
        atomicAdd(&g_hist[ch * KBINS + (k - 1)], t);
    }
}

__global__ void __launch_bounds__(256)
binloss_final(const int* __restrict__ g_hist, const float* __restrict__ partials,
              float* __restrict__ out)
{
    __shared__ double r1[256];
    __shared__ double r2[256];
    const int tid = threadIdx.x;
    double s1 = 0.0, s2 = 0.0;
    for (int i = tid; i < NBLOCKS; i += 256) s1 += (double)partials[i];
    for (int i = tid; i < BC * KBINS; i += 256) s2 += fabs((double)g_hist[i]);
    r1[tid] = s1; r2[tid] = s2;
    __syncthreads();
    for (int off = 128; off > 0; off >>= 1) {
        if (tid < off) { r1[tid] += r1[tid + off]; r2[tid] += r2[tid + off]; }
        __syncthreads();
    }
    if (tid == 0) {
        const double ntot  = (double)BC * (double)NVOX;
        double loss1 = r1[0] / ntot;
        double loss2 = r2[0] / ((double)NVOX * (double)(BC * KBINS));
        out[0] = (float)(0.5 * loss1 + 0.5 * loss2);
    }
}

extern "C" void kernel_launch(void* const* d_in, const int* in_sizes, int n_in,
                              void* d_out, int out_size, void* d_ws, size_t ws_size,
                              hipStream_t stream) {
    const float* inp = (const float*)d_in[0];
    const float* tar = (const float*)d_in[1];
    const float* br  = (const float*)d_in[2];

    int*   g_hist   = (int*)d_ws;
    float* partials = (float*)((char*)d_ws + BC * KBINS * sizeof(int));

    // histogram is accumulated with atomics -> must be zeroed every call
    hipMemsetAsync(d_ws, 0, BC * KBINS * sizeof(int), stream);

    binloss_main<<<NBLOCKS, THREADS, 0, stream>>>(inp, tar, br, g_hist, partials);
    binloss_final<<<1, 256, 0, stream>>>(g_hist, partials, (float*)d_out);
}